// Round 4
// baseline (766.159 us; speedup 1.0000x reference)
//
#include <hip/hip_runtime.h>

constexpr int NPIX = 196608;
constexpr int FF   = 32;
constexpr size_t SLOT = (size_t)NPIX * FF;

typedef short bf16x8 __attribute__((ext_vector_type(8)));
typedef float f32x4  __attribute__((ext_vector_type(4)));

__device__ __forceinline__ float blo(uint u) {
    union { float f; uint i; } v; v.i = u << 16; return v.f;
}
__device__ __forceinline__ float bhi(uint u) {
    union { float f; uint i; } v; v.i = u & 0xffff0000u; return v.f;
}
__device__ __forceinline__ ushort f2b(float f) {
    union { float f; uint i; } v; v.f = f;
    uint r = v.i + 0x7fffu + ((v.i >> 16) & 1u);   // RNE
    return (ushort)(r >> 16);
}
__device__ __forceinline__ uint pack2(float lo, float hi) {
    return ((uint)f2b(hi) << 16) | (uint)f2b(lo);
}

// ---------------- fp32 -> bf16 convert (maps -> chain T0) ----------------
__global__ __launch_bounds__(256) void f2b_kernel(const float* __restrict__ src,
                                                  ushort* __restrict__ dst) {
    int i = (blockIdx.x * 256 + threadIdx.x) * 4;
    float4 v = *reinterpret_cast<const float4*>(src + i);
    ushort4 o;
    o.x = f2b(v.x); o.y = f2b(v.y); o.z = f2b(v.z); o.w = f2b(v.w);
    *reinterpret_cast<ushort4*>(dst + i) = o;
}

// ------- Chebyshev step: 4 lanes/node, uint4 (8-feature) gathers, 1KB/instr -------
// INIT: Tout = L(Tprev).  else: Tout = 2 L(Tprev) - Told.
template<int NB, bool INIT>
__global__ __launch_bounds__(256, 4) void cheb_step4(
    const ushort* __restrict__ Tprev,
    const ushort* __restrict__ Told,
    ushort*       __restrict__ Tout,
    const int*    __restrict__ idx,
    const float*  __restrict__ wnb)
{
    int t = blockIdx.x * 256 + threadIdx.x;
    int n = t >> 2;          // node
    int h = t & 3;           // feature octet: features [h*8, h*8+8)

    const int4*   ip = reinterpret_cast<const int4*>(idx + (size_t)n * NB);
    const float4* wv = reinterpret_cast<const float4*>(wnb + (size_t)n * NB);
    int4   I[NB / 4];
    float4 W[NB / 4];
#pragma unroll
    for (int j = 0; j < NB / 4; ++j) { I[j] = ip[j]; W[j] = wv[j]; }

    const uint4* Tp = reinterpret_cast<const uint4*>(Tprev);
    float s0 = 0.f, s1 = 0.f, s2 = 0.f, s3 = 0.f;
    float s4 = 0.f, s5 = 0.f, s6 = 0.f, s7 = 0.f;

#pragma unroll
    for (int j = 0; j < NB / 4; ++j) {
        int4 i4 = I[j]; float4 w4 = W[j];
        {
            uint4 u = Tp[(size_t)i4.x * 4 + h];
            s0 += w4.x * blo(u.x); s1 += w4.x * bhi(u.x);
            s2 += w4.x * blo(u.y); s3 += w4.x * bhi(u.y);
            s4 += w4.x * blo(u.z); s5 += w4.x * bhi(u.z);
            s6 += w4.x * blo(u.w); s7 += w4.x * bhi(u.w);
        }
        {
            uint4 u = Tp[(size_t)i4.y * 4 + h];
            s0 += w4.y * blo(u.x); s1 += w4.y * bhi(u.x);
            s2 += w4.y * blo(u.y); s3 += w4.y * bhi(u.y);
            s4 += w4.y * blo(u.z); s5 += w4.y * bhi(u.z);
            s6 += w4.y * blo(u.w); s7 += w4.y * bhi(u.w);
        }
        {
            uint4 u = Tp[(size_t)i4.z * 4 + h];
            s0 += w4.z * blo(u.x); s1 += w4.z * bhi(u.x);
            s2 += w4.z * blo(u.y); s3 += w4.z * bhi(u.y);
            s4 += w4.z * blo(u.z); s5 += w4.z * bhi(u.z);
            s6 += w4.z * blo(u.w); s7 += w4.z * bhi(u.w);
        }
        {
            uint4 u = Tp[(size_t)i4.w * 4 + h];
            s0 += w4.w * blo(u.x); s1 += w4.w * bhi(u.x);
            s2 += w4.w * blo(u.y); s3 += w4.w * bhi(u.y);
            s4 += w4.w * blo(u.z); s5 += w4.w * bhi(u.z);
            s6 += w4.w * blo(u.w); s7 += w4.w * bhi(u.w);
        }
    }

    size_t base = (size_t)n * 4 + h;
    uint4 o;
    if (INIT) {
        o.x = pack2(s0, s1); o.y = pack2(s2, s3);
        o.z = pack2(s4, s5); o.w = pack2(s6, s7);
    } else {
        uint4 told = reinterpret_cast<const uint4*>(Told)[base];
        o.x = pack2(2.f * s0 - blo(told.x), 2.f * s1 - bhi(told.x));
        o.y = pack2(2.f * s2 - blo(told.y), 2.f * s3 - bhi(told.y));
        o.z = pack2(2.f * s4 - blo(told.z), 2.f * s5 - bhi(told.z));
        o.w = pack2(2.f * s6 - blo(told.w), 2.f * s7 - bhi(told.w));
    }
    reinterpret_cast<uint4*>(Tout)[base] = o;
}

// ----- finish: out = relu([N,K*32] @ W2 + b) -> LN -> (+resid), W2 built in-block -----
// W2[(k,f)][g] = wd[k][f][0]*wp[2f][g] + wd[k][f][1]*wp[2f+1][g]; stored transposed
// in LDS as sW[g][k*32+f] (bf16, padded). A-frags load straight from global.
template<int K, bool RESIDUAL, bool OUT_BF16>
__global__ __launch_bounds__(256, 4) void finish_gemm(
    const ushort* __restrict__ chain,  // K contiguous bf16 [N][32] slots
    const float*  __restrict__ wd,     // [K][32][2]
    const float*  __restrict__ wp,     // [64][32]
    const float*  __restrict__ bias,
    const float*  __restrict__ gamma,
    const float*  __restrict__ beta,
    const float*  __restrict__ resid,  // fp32 maps or nullptr
    void*         __restrict__ outp)   // ushort* (bf16) or float*
{
    constexpr int KW = K * 32;               // 192 or 320
    constexpr int WSTRIDE = KW + 8;          // ushort stride (16B pad)
    __shared__ float swp[64 * 33];           // wp staged, padded (+1 dword/row)
    __shared__ __align__(16) ushort sW[32][WSTRIDE];

    int tid = threadIdx.x;
    int wv = tid >> 6, l = tid & 63;
    int r = l & 15, hi = l >> 4;
    int nbase = blockIdx.x * 64 + wv * 16;

    // ---- A prefetch: perfectly coalesced 16B/lane, issued before LDS phases ----
    bf16x8 aF[K];
#pragma unroll
    for (int k = 0; k < K; ++k)
        aF[k] = *reinterpret_cast<const bf16x8*>(
            chain + (size_t)k * SLOT + (size_t)(nbase + r) * FF + hi * 8);

    // ---- stage wp into padded LDS (coalesced) ----
    for (int i = tid; i < 64 * 32; i += 256) {
        int u = i >> 5, g = i & 31;
        swp[u * 33 + g] = wp[i];
    }
    __syncthreads();

    // ---- build W2^T in LDS: sW[g][k*32+f] ----
    for (int i = tid; i < 32 * KW; i += 256) {
        int g = i / KW, kf = i - g * KW;     // consecutive lanes: same g, kf+1
        int f = kf & 31;
        float2 wdv = *reinterpret_cast<const float2*>(wd + (size_t)kf * 2);
        float w2 = wdv.x * swp[(2 * f) * 33 + g] + wdv.y * swp[(2 * f + 1) * 33 + g];
        sW[g][kf] = f2b(w2);
    }
    __syncthreads();

    // ---- GEMM: D[16,32] = A[16,KW] @ W2[KW,32], two 16-wide g tiles ----
    f32x4 acc0 = {0.f, 0.f, 0.f, 0.f};
    f32x4 acc1 = {0.f, 0.f, 0.f, 0.f};
#pragma unroll
    for (int k = 0; k < K; ++k) {
        bf16x8 b0 = *reinterpret_cast<const bf16x8*>(&sW[r][k * 32 + hi * 8]);
        bf16x8 b1 = *reinterpret_cast<const bf16x8*>(&sW[16 + r][k * 32 + hi * 8]);
        acc0 = __builtin_amdgcn_mfma_f32_16x16x32_bf16(aF[k], b0, acc0, 0, 0, 0);
        acc1 = __builtin_amdgcn_mfma_f32_16x16x32_bf16(aF[k], b1, acc1, 0, 0, 0);
    }

    // ---- epilogue: bias+relu, LN over 32 features, optional residual ----
    float bias_lo = bias[r],  bias_hi = bias[16 + r];
    float gam_lo  = gamma[r], gam_hi  = gamma[16 + r];
    float bet_lo  = beta[r],  bet_hi  = beta[16 + r];

#pragma unroll
    for (int v = 0; v < 4; ++v) {
        acc0[v] = fmaxf(acc0[v] + bias_lo, 0.f);
        acc1[v] = fmaxf(acc1[v] + bias_hi, 0.f);
    }
#pragma unroll
    for (int v = 0; v < 4; ++v) {
        float s1 = acc0[v] + acc1[v];
        float s2 = acc0[v] * acc0[v] + acc1[v] * acc1[v];
#pragma unroll
        for (int m = 1; m < 16; m <<= 1) {
            s1 += __shfl_xor(s1, m);
            s2 += __shfl_xor(s2, m);
        }
        float mu  = s1 * (1.f / 32.f);
        float var = s2 * (1.f / 32.f) - mu * mu;
        float rs  = rsqrtf(var + 1e-6f);
        int n = nbase + hi * 4 + v;
        size_t o0 = (size_t)n * FF + r;
        size_t o1 = o0 + 16;
        float z0 = (acc0[v] - mu) * rs * gam_lo + bet_lo;
        float z1 = (acc1[v] - mu) * rs * gam_hi + bet_hi;
        if (RESIDUAL) { z0 += resid[o0]; z1 += resid[o1]; }
        if (OUT_BF16) {
            ((ushort*)outp)[o0] = f2b(z0);
            ((ushort*)outp)[o1] = f2b(z1);
        } else {
            ((float*)outp)[o0] = z0;
            ((float*)outp)[o1] = z1;
        }
    }
}

extern "C" void kernel_launch(void* const* d_in, const int* in_sizes, int n_in,
                              void* d_out, int out_size, void* d_ws, size_t ws_size,
                              hipStream_t stream) {
    const float* maps = (const float*)d_in[0];
    const int*   idx1 = (const int*)  d_in[1];
    const float* w1nb = (const float*)d_in[2];
    const int*   idx2 = (const int*)  d_in[3];
    const float* w2nb = (const float*)d_in[4];
    const float* wd1  = (const float*)d_in[5];
    const float* wp1  = (const float*)d_in[6];
    const float* b1   = (const float*)d_in[7];
    const float* g1   = (const float*)d_in[8];
    const float* be1  = (const float*)d_in[9];
    const float* wd2  = (const float*)d_in[10];
    const float* wp2  = (const float*)d_in[11];
    const float* b2   = (const float*)d_in[12];
    const float* g2   = (const float*)d_in[13];
    const float* be2  = (const float*)d_in[14];
    float* out = (float*)d_out;

    // ws: exactly 10 bf16 slots (120 MiB). Layer-2 chain B0..B9 = slots 0..9;
    // layer-1 chain A0..A5 = slots 4..9 (consumed by finish1 before overwrite).
    ushort* slots = (ushort*)d_ws;
    ushort* B = slots;
    ushort* A = slots + 4 * SLOT;

    const int stepBlocks = NPIX * 4 / 256;        // 3072
    const int cvtBlocks  = NPIX * FF / (256 * 4); // 6144
    const int finBlocks  = NPIX / 64;             // 3072

    // ---------------- layer 1: K=6, NB=8 ----------------
    f2b_kernel<<<cvtBlocks, 256, 0, stream>>>(maps, A);                               // A0
    cheb_step4<8, true><<<stepBlocks, 256, 0, stream>>>(A, nullptr, A + SLOT, idx1, w1nb);  // A1
    cheb_step4<8, false><<<stepBlocks, 256, 0, stream>>>(A + SLOT,     A,              A + 2 * SLOT, idx1, w1nb);
    cheb_step4<8, false><<<stepBlocks, 256, 0, stream>>>(A + 2 * SLOT, A + SLOT,       A + 3 * SLOT, idx1, w1nb);
    cheb_step4<8, false><<<stepBlocks, 256, 0, stream>>>(A + 3 * SLOT, A + 2 * SLOT,   A + 4 * SLOT, idx1, w1nb);
    cheb_step4<8, false><<<stepBlocks, 256, 0, stream>>>(A + 4 * SLOT, A + 3 * SLOT,   A + 5 * SLOT, idx1, w1nb);
    finish_gemm<6, false, true><<<finBlocks, 256, 0, stream>>>(A, wd1, wp1, b1, g1, be1, nullptr, B);  // -> B0

    // ---------------- layer 2: K=10, NB=20 ----------------
    cheb_step4<20, true><<<stepBlocks, 256, 0, stream>>>(B, nullptr, B + SLOT, idx2, w2nb);  // B1
    for (int k = 2; k <= 9; ++k)
        cheb_step4<20, false><<<stepBlocks, 256, 0, stream>>>(
            B + (size_t)(k - 1) * SLOT, B + (size_t)(k - 2) * SLOT,
            B + (size_t)k * SLOT, idx2, w2nb);
    finish_gemm<10, true, false><<<finBlocks, 256, 0, stream>>>(B, wd2, wp2, b2, g2, be2, maps, out);
}